// Round 8
// baseline (49951.260 us; speedup 1.0000x reference)
//
#include <hip/hip_runtime.h>

typedef unsigned short u16;
typedef unsigned int u32;
typedef unsigned long long u64;
typedef _Float16 f16;
typedef __attribute__((ext_vector_type(8))) _Float16 f16x8;
typedef __attribute__((ext_vector_type(4))) float f32x4;

#define TT 512
#define DD 64
#define SC 2048.0f
#define ISC (1.0f / 2048.0f)

// Activation buffers (H1/H2): f16 hi/lo-split pairs, MFMA-fragment layout:
// [mtile(16)][ks(32: 0-15 hi, 16-31 lo*2^11)][1KB frag]. Weight B-frags split
// into H and L (L pre-scaled by 2^11; true value = H + L/2^11).
//
// STRUCTURE (R8): 128 blocks x 512 threads; block = (mtile mt, 8 J-columns);
// wave wv (0..7) owns J = Jblk*8+wv, FULL K (no kh split -> no LDS exchange;
// per-row z1 scaling handled with two accumulator sets per cell).
// Registration (HW_REG_XCC_ID, R7-verified) sets Jblk=xcc, mt=rank so each
// XCD's weight slice (~2.2MB: 8 J's of PB1a/PB1b/PB2a/PB2b/PB1x + PBo) stays
// L2-resident. Fallback mapping (bid-based) is correctness-identical.
// Cross-XCD H1/H2 traffic: epilogue stores = 2B agent atomics (MALL);
// staging loads = 16B sc0+sc1 (device-coherent, cache-bypassing); z-rows and
// out-tiles read the block's LDS copy. 2 global barriers/step (monotonic).
struct WS {
  f16 *PB1aH, *PB1aL, *PB1bH, *PB1bL, *PB1xH, *PB1xL;
  f16 *PB2aH, *PB2aL, *PB2bH, *PB2bL, *PBo;
  float *wz1, *wz2, *b1f, *b2f, *bof;
  f16 *H1[2], *H2[2];
  float *c1, *c2, *h2m;
  float *z1[2], *z2[2];
  int *bar;   // [grp*32] cnts, [256] root, [288+grp*32] gens, [544+xcc*8] regcnt
  int *flag;  // 1 = inputs are float32, 0 = inputs are bf16
};

__device__ __forceinline__ float bf2f(u16 u) { return __uint_as_float(((u32)u) << 16); }
__device__ __forceinline__ u16 f2bf(float f) {
  u32 u = __float_as_uint(f);
  u += 0x7fffu + ((u >> 16) & 1u);
  return (u16)(u >> 16);
}
__device__ __forceinline__ float ldw(const void* p, size_t i, int f32) {
  return f32 ? ((const float*)p)[i] : bf2f(((const u16*)p)[i]);
}
__device__ __forceinline__ float sigm(float x) { return 1.0f / (1.0f + expf(-x)); }
__device__ __forceinline__ f16x8 ldf(const f16* p) { return *(const f16x8*)p; }

// ---- agent-scope (MALL) accessors ----
__device__ __forceinline__ f16x8 ldc(const f16* p) {  // 16B via 2x8B atomics
  union { u64 u[2]; f16x8 v; } r;
  r.u[0] = __hip_atomic_load((const u64*)p,     __ATOMIC_RELAXED, __HIP_MEMORY_SCOPE_AGENT);
  r.u[1] = __hip_atomic_load((const u64*)p + 1, __ATOMIC_RELAXED, __HIP_MEMORY_SCOPE_AGENT);
  return r.v;
}
__device__ __forceinline__ void stc16(f16* p, f16 v) {
  u16 b;
  __builtin_memcpy(&b, &v, 2);
  __hip_atomic_store((u16*)p, b, __ATOMIC_RELAXED, __HIP_MEMORY_SCOPE_AGENT);
}
__device__ __forceinline__ float ldcf(const float* p) {
  return __hip_atomic_load(p, __ATOMIC_RELAXED, __HIP_MEMORY_SCOPE_AGENT);
}
__device__ __forceinline__ void stcf(float* p, float v) {
  __hip_atomic_store(p, v, __ATOMIC_RELAXED, __HIP_MEMORY_SCOPE_AGENT);
}

// 4x16B device-coherent loads (sc0 sc1: bypass L1+L2, served at MALL) -> LDS.
// Same cache-control bits the agent atomics use; 2x the grain. No atomicity
// needed: global barrier fully separates producers from consumers.
__device__ __forceinline__ void stage4(const f16* __restrict__ g,
                                       f16* __restrict__ l, int tid)
{
  f16x8 a0, a1, a2, a3;
  const f16* p = g + (size_t)tid * 8;
  asm volatile(
    "global_load_dwordx4 %0, %4, off sc0 sc1\n\t"
    "global_load_dwordx4 %1, %5, off sc0 sc1\n\t"
    "global_load_dwordx4 %2, %6, off sc0 sc1\n\t"
    "global_load_dwordx4 %3, %7, off sc0 sc1\n\t"
    "s_waitcnt vmcnt(0)"
    : "=&v"(a0), "=&v"(a1), "=&v"(a2), "=&v"(a3)
    : "v"(p), "v"(p + 4096), "v"(p + 8192), "v"(p + 12288)
    : "memory");
  *(f16x8*)(l + tid * 8)         = a0;
  *(f16x8*)(l + tid * 8 + 4096)  = a1;
  *(f16x8*)(l + tid * 8 + 8192)  = a2;
  *(f16x8*)(l + tid * 8 + 12288) = a3;
}

__device__ __forceinline__ double shfl_down_dbl(double v, int off) {
  const int lo = __shfl_down(__double2loint(v), off);
  const int hi = __shfl_down(__double2hiint(v), off);
  return __hiloint2double(hi, lo);
}

#define MFMA(a, b, c) __builtin_amdgcn_mfma_f32_16x16x32_f16(a, b, c, 0, 0, 0)

// -------- global barrier: MONOTONIC, relaxed-only, epoch k (1-based) --------
// 128 blocks, 8 groups of 16 (grp = bid&7). No counter resets. Timeout =
// container safety only.
__device__ __forceinline__ void gridbar(int* __restrict__ bar, int grp, int k)
{
  __syncthreads();
  if (threadIdx.x == 0) {
    int* myc   = bar + grp * 32;
    int* gens  = bar + 288;
    int* mygen = gens + grp * 32;
    if (__hip_atomic_fetch_add(myc, 1, __ATOMIC_RELAXED,
                               __HIP_MEMORY_SCOPE_AGENT) + 1 == 16 * k) {
      if (__hip_atomic_fetch_add(bar + 256, 1, __ATOMIC_RELAXED,
                                 __HIP_MEMORY_SCOPE_AGENT) + 1 == 8 * k) {
#pragma unroll
        for (int i = 0; i < 8; ++i)
          __hip_atomic_fetch_add(gens + i * 32, 1, __ATOMIC_RELAXED,
                                 __HIP_MEMORY_SCOPE_AGENT);
      }
    }
    const long long t0 = (long long)__builtin_amdgcn_s_memrealtime();
    while (__hip_atomic_load(mygen, __ATOMIC_RELAXED,
                             __HIP_MEMORY_SCOPE_AGENT) < k) {
      __builtin_amdgcn_s_sleep(2);
      if ((long long)__builtin_amdgcn_s_memrealtime() - t0 > 2000000LL) break;
    }
  }
  __syncthreads();
}

// ---------------- dtype detection ----------------
__global__ void detect_kernel(const u16* __restrict__ x, int* __restrict__ flag)
{
  int tid = threadIdx.x;  // 64 threads
  int cnt = 0;
  for (int i = tid; i < 8192; i += 64) {
    int e = (x[i] >> 7) & 0xFF;
    cnt += (e >= 0xC0 || (e != 0 && e < 0x30)) ? 1 : 0;
  }
#pragma unroll
  for (int off = 32; off; off >>= 1) cnt += __shfl_down(cnt, off);
  if (tid == 0) *flag = (cnt > 100) ? 1 : 0;
}

// ---------------- prologue: weight packing ----------------
__device__ __forceinline__ void packGate(const void* __restrict__ U,
                                         f16* __restrict__ dstH, f16* __restrict__ dstL,
                                         int g, int KS, int F32) {
  int lane = g & 63;
  int rest = g >> 6;
  int t2 = rest & 1; rest >>= 1;
  int ks = rest % KS;
  int J  = rest / KS;
  int q = lane >> 4, n = lane & 15;
  int j = J * 8 + (n & 7);
  int c = (t2 * 2 + (n >> 3)) * 512 + j;
  int kb = ks * 32 + q * 8;
  f16 vh[8], vl[8];
#pragma unroll
  for (int i = 0; i < 8; ++i) {
    float v = ldw(U, (size_t)(kb + i) * 2049 + c, F32);
    f16 h = (f16)v;
    vh[i] = h;
    vl[i] = (f16)((v - (float)h) * SC);
  }
  *(f16x8*)(dstH + (size_t)g * 8) = *(f16x8*)vh;
  *(f16x8*)(dstL + (size_t)g * 8) = *(f16x8*)vl;
}

#define NPACK (4 * 131072 + 16384 + 8192 + 2112 + 2048 + 2049 + 2049 + 64)

__global__ __launch_bounds__(256) void pack_kernel(
    const void* __restrict__ U11_1, const void* __restrict__ U21_1,
    const void* __restrict__ W01_1, const void* __restrict__ bias1,
    const void* __restrict__ U11_2, const void* __restrict__ W01_2,
    const void* __restrict__ bias2, const void* __restrict__ l1W,
    const void* __restrict__ l1b, const void* __restrict__ l2W,
    const void* __restrict__ l2b, WS w)
{
  const int F32 = *w.flag;
  int gid = blockIdx.x * 256 + threadIdx.x;
  const int NG = 131072;
  if (gid < NG) { packGate(U11_1, w.PB1aH, w.PB1aL, gid, 16, F32); return; }
  gid -= NG;
  if (gid < NG) { packGate(U21_1, w.PB1bH, w.PB1bL, gid, 16, F32); return; }
  gid -= NG;
  if (gid < NG) { packGate(U11_2, w.PB2aH, w.PB2aL, gid, 16, F32); return; }
  gid -= NG;
  if (gid < NG) { packGate(W01_2, w.PB2bH, w.PB2bL, gid, 16, F32); return; }
  gid -= NG;
  if (gid < 16384) { packGate(W01_1, w.PB1xH, w.PB1xL, gid, 2, F32); return; }
  gid -= 16384;
  if (gid < 8192) {  // PBo (hi only): [w4][ks 0..31][lane][8]
    int lane = gid & 63;
    int rest = gid >> 6;
    int ks = rest & 31;
    int w4 = rest >> 5;
    int q = lane >> 4;
    int d = w4 * 16 + (lane & 15);
    int kb = ks * 32 + q * 8;
    f16 v[8];
#pragma unroll
    for (int i = 0; i < 8; ++i) {
      int k = kb + i;
      float s = (k < 512) ? ldw(l1W, (size_t)d * 512 + k, F32)
                          : ldw(l2W, (size_t)d * 512 + (k - 512), F32);
      v[i] = (f16)s;
    }
    *(f16x8*)(w.PBo + (size_t)gid * 8) = *(f16x8*)v;
    return;
  }
  gid -= 8192;
  if (gid < 2112) {  // z-column weights, cell1 (fp32 exact)
    int i = gid; float s;
    if (i < 512)       s = ldw(U11_1, (size_t)i * 2049 + 2048, F32);
    else if (i < 1024) s = ldw(U11_1, (size_t)(i - 512) * 2049 + 2048, F32);
    else if (i < 1536) s = ldw(U21_1, (size_t)(i - 1024) * 2049 + 2048, F32);
    else if (i < 2048) s = ldw(U21_1, (size_t)(i - 1536) * 2049 + 2048, F32);
    else               s = ldw(W01_1, (size_t)(i - 2048) * 2049 + 2048, F32);
    w.wz1[i] = s; return;
  }
  gid -= 2112;
  if (gid < 2048) {  // z-column weights, cell2
    int i = gid; float s;
    if (i < 512)       s = ldw(U11_2, (size_t)i * 2049 + 2048, F32);
    else if (i < 1024) s = ldw(U11_2, (size_t)(i - 512) * 2049 + 2048, F32);
    else if (i < 1536) s = ldw(W01_2, (size_t)(i - 1024) * 2049 + 2048, F32);
    else               s = ldw(W01_2, (size_t)(i - 1536) * 2049 + 2048, F32);
    w.wz2[i] = s; return;
  }
  gid -= 2048;
  if (gid < 2049) { w.b1f[gid] = ldw(bias1, gid, F32); return; }
  gid -= 2049;
  if (gid < 2049) { w.b2f[gid] = ldw(bias2, gid, F32); return; }
  gid -= 2049;
  if (gid < 64) { w.bof[gid] = ldw(l1b, gid, F32) + ldw(l2b, gid, F32); return; }
}

__global__ __launch_bounds__(256) void init_kernel(WS w)
{
  size_t id = (size_t)blockIdx.x * 256 + threadIdx.x;
  const size_t nw = 131072;  // u32 words per f16 state buffer
  if (id < 2 * nw) {
    u32* p = (id < nw) ? (u32*)w.H1[1] : (u32*)w.H2[1];
    p[id % nw] = 0u;
    return;
  }
  id -= 2 * nw;
  const size_t nf = 131072;
  if (id < 3 * nf) {
    float* p = (id < nf) ? w.c1 : (id < 2 * nf) ? w.c2 : w.h2m;
    p[id % nf] = 0.0f;
    return;
  }
  id -= 3 * nf;
  if (id < 512) {
    ((id < 256) ? w.z1[1] : w.z2[1])[id & 255] = 0.0f;
    return;
  }
  id -= 512;
  if (id < 2048) w.bar[id] = 0;  // barrier + registration state (each replay)
}

// ------- z-logit rows from the block's LDS copy (one wave, fp64 reduce) ------
__device__ __forceinline__ void z1_row_lds(const WS& w, const void* __restrict__ x,
    const f16* __restrict__ sA, const f16* __restrict__ sH2,
    int F32, int t, int pp, int pc, int b, int lane)
{
  const int ks = lane >> 2;   // 0..15
  const int qq = lane & 3;    // 0..3
  const int j = ks * 32 + qq * 8;
  const int lf = (b & 15) * 8 + ks * 512 + qq * 128;
  f16x8 h8 = *(const f16x8*)(sA + lf),  l8 = *(const f16x8*)(sA + lf + 8192);
  f16x8 g8 = *(const f16x8*)(sH2 + lf), m8 = *(const f16x8*)(sH2 + lf + 8192);
  double aa = 0.0, az = 0.0;
#pragma unroll
  for (int i = 0; i < 8; ++i) {
    double ha = (double)(float)h8[i] + (double)(float)l8[i] * (1.0 / 2048.0);
    double hz = (double)(float)g8[i] + (double)(float)m8[i] * (1.0 / 2048.0);
    aa += ha * (double)w.wz1[j + i];
    az += hz * (double)w.wz1[1024 + j + i];
  }
  {
    float xv = ldw(x, ((size_t)b * TT + t) * DD + lane, F32);
    aa += (double)xv * (double)w.wz1[2048 + lane];
  }
#pragma unroll
  for (int off = 32; off; off >>= 1) {
    aa += shfl_down_dbl(aa, off);
    az += shfl_down_dbl(az, off);
  }
  if (lane == 0) {
    const double z1p = (double)ldcf(w.z1[pp] + b);
    float sz = (float)(aa + z1p * az + (double)w.b1f[2048]);
    float zh = (sz + 1.0f) * 0.5f;  // round-half-even(zh) == (zh > 0.5)
    stcf(w.z1[pc] + b, (zh > 0.5f) ? 1.0f : 0.0f);
  }
}

__device__ __forceinline__ void z2_row_lds(const WS& w,
    const f16* __restrict__ sH2 /*H2[pp]*/, const f16* __restrict__ sA /*H1[pc]*/,
    int pc, int b, int lane)
{
  const int ks = lane >> 2;
  const int qq = lane & 3;
  const int j = ks * 32 + qq * 8;
  const int lf = (b & 15) * 8 + ks * 512 + qq * 128;
  f16x8 h8  = *(const f16x8*)(sH2 + lf), l8  = *(const f16x8*)(sH2 + lf + 8192);
  f16x8 h8b = *(const f16x8*)(sA + lf),  l8b = *(const f16x8*)(sA + lf + 8192);
  double da = 0.0, db = 0.0;
#pragma unroll
  for (int i = 0; i < 8; ++i) {
    double ha = (double)(float)h8[i]  + (double)(float)l8[i]  * (1.0 / 2048.0);
    double hb = (double)(float)h8b[i] + (double)(float)l8b[i] * (1.0 / 2048.0);
    da += ha * (double)w.wz2[j + i];
    db += hb * (double)w.wz2[1024 + j + i];
  }
#pragma unroll
  for (int off = 32; off; off >>= 1) {
    da += shfl_down_dbl(da, off);
    db += shfl_down_dbl(db, off);
  }
  if (lane == 0) {
    const double z1n = (double)ldcf(w.z1[pc] + b);
    float sz = (float)(da + z1n * db + (double)w.b2f[2048]);
    stcf(w.z2[pc] + b, (((sz + 1.0f) * 0.5f) > 0.5f) ? 1.0f : 0.0f);
  }
}

// ---- out(t-1) from LDS (phase A: sA=H1[pp], sH2=H2[pp]; hi sections) -------
__device__ __forceinline__ void out_tile_lds(const WS& w, void* __restrict__ out,
    const f16* __restrict__ sA, const f16* __restrict__ sH2,
    int F32, int twrite, int mt, int w4, int lane)
{
  const f16* Bo = w.PBo + (size_t)w4 * 16384 + lane * 8;
  const f16* A1 = sA + lane * 8;
  const f16* A2 = sH2 + lane * 8;
  f32x4 acc = {0.f, 0.f, 0.f, 0.f};
#pragma unroll
  for (int k = 0; k < 16; ++k)
    acc = MFMA(*(const f16x8*)(A1 + k * 512), ldf(Bo + k * 512), acc);
#pragma unroll
  for (int k = 0; k < 16; ++k)
    acc = MFMA(*(const f16x8*)(A2 + k * 512), ldf(Bo + (16 + k) * 512), acc);
  const int q = lane >> 4;
  const int d = w4 * 16 + (lane & 15);
  const float bias = w.bof[d];
#pragma unroll
  for (int r = 0; r < 4; ++r) {
    const int b = mt * 16 + q * 4 + r;
    const size_t idx = ((size_t)b * TT + twrite) * DD + d;
    const float val = acc[r] + bias;
    if (F32) ((float*)out)[idx] = val;
    else     ((u16*)out)[idx] = f2bf(val);
  }
}

// ---- final out (t=511): global read via MALL atomics (runs once) -----------
__device__ __forceinline__ void out_tile_g(const WS& w, void* __restrict__ out,
                                           int F32, int pq, int twrite, int ot,
                                           int w4, int lane)
{
  const f16* A1 = w.H1[pq] + (size_t)ot * 16384 + lane * 8;
  const f16* A2 = w.H2[pq] + (size_t)ot * 16384 + lane * 8;
  const f16* Bo = w.PBo + (size_t)w4 * 16384 + lane * 8;
  f32x4 acc = {0.f, 0.f, 0.f, 0.f};
#pragma unroll
  for (int k = 0; k < 16; ++k) acc = MFMA(ldc(A1 + k * 512), ldf(Bo + k * 512), acc);
#pragma unroll
  for (int k = 0; k < 16; ++k) acc = MFMA(ldc(A2 + k * 512), ldf(Bo + (16 + k) * 512), acc);
  const int q = lane >> 4;
  const int d = w4 * 16 + (lane & 15);
  const float bias = w.bof[d];
#pragma unroll
  for (int r = 0; r < 4; ++r) {
    const int b = ot * 16 + q * 4 + r;
    const size_t idx = ((size_t)b * TT + twrite) * DD + d;
    const float val = acc[r] + bias;
    if (F32) ((float*)out)[idx] = val;
    else     ((u16*)out)[idx] = f2bf(val);
  }
}

// ---------------- persistent kernel: full 512-step recurrence ----------------
__global__ __launch_bounds__(512) void persist(const void* __restrict__ x,
                                               void* __restrict__ out, WS w)
{
  __shared__ f16 sA[16384];   // 32KB: phA = H1[pp][mt]; phB = H1[pc][mt]
  __shared__ f16 sH2[16384];  // 32KB: H2[pp][mt] (staged phA, used phA+phB)
  __shared__ int sreg[3];
  const int F32 = *w.flag;
  const int bid = blockIdx.x;
  const int tid = threadIdx.x;
  const int lane = tid & 63, wv = tid >> 6;   // wv 0..7
  const int grp = bid & 7;
  // ---- XCD registration (mapping only; data path is mode-independent) ----
  if (tid == 0) {
    const int xcc = __builtin_amdgcn_s_getreg((31 << 11) | 20) & 7;  // HW_REG_XCC_ID
    const int rank = __hip_atomic_fetch_add(w.bar + 544 + xcc * 8, 1,
                                            __ATOMIC_RELAXED, __HIP_MEMORY_SCOPE_AGENT);
    sreg[0] = xcc;
    sreg[1] = rank;
  }
  gridbar(w.bar, grp, 1);
  if (tid == 0) {
    int ok = 1;
#pragma unroll
    for (int i = 0; i < 8; ++i)
      ok &= (__hip_atomic_load(w.bar + 544 + i * 8, __ATOMIC_RELAXED,
                               __HIP_MEMORY_SCOPE_AGENT) == 16);
    sreg[2] = ok;
  }
  __syncthreads();
  const int lok  = sreg[2];
  const int Jblk = lok ? sreg[0] : (bid & 7);   // XCD-resident weight slice
  const int mt   = lok ? sreg[1] : (bid >> 3);  // 0..15

  const int J = Jblk * 8 + wv;
  const int m0 = mt * 16;
  const int q = lane >> 4;
  const int jcol = J * 8 + (lane & 7);
  const bool ilane = (lane & 8) != 0;
  const int r0 = ilane ? 2 : 0;
  const float b1ff = w.b1f[jcol], b1fi = w.b1f[512 + jcol];
  const float b1fo = w.b1f[1024 + jcol], b1fg = w.b1f[1536 + jcol];
  const float b2ff = w.b2f[jcol], b2fi = w.b2f[512 + jcol];
  const float b2fo = w.b2f[1024 + jcol], b2fg = w.b2f[1536 + jcol];
  const int zb0 = mt * 16 + Jblk * 2;           // this block's 2 z-rows
  const bool doOut = (Jblk < 4);
  // weight base pointers for this wave's J column
  const f16* BaH = w.PB1aH + (size_t)J * 16384 + lane * 8;
  const f16* BaL = w.PB1aL + (size_t)J * 16384 + lane * 8;
  const f16* BbH = w.PB1bH + (size_t)J * 16384 + lane * 8;
  const f16* BbL = w.PB1bL + (size_t)J * 16384 + lane * 8;
  const f16* BxH = w.PB1xH + (size_t)J * 2048  + lane * 8;
  const f16* BxL = w.PB1xL + (size_t)J * 2048  + lane * 8;
  const f16* CaH = w.PB2aH + (size_t)J * 16384 + lane * 8;
  const f16* CaL = w.PB2aL + (size_t)J * 16384 + lane * 8;
  const f16* CbH = w.PB2bH + (size_t)J * 16384 + lane * 8;
  const f16* CbL = w.PB2bL + (size_t)J * 16384 + lane * 8;

  for (int t = 0; t < 512; ++t) {
    const int pc = t & 1, pp = pc ^ 1;
    // ================= phase A: cell 1 =================
    stage4(w.H1[pp] + (size_t)mt * 16384, sA, tid);
    stage4(w.H2[pp] + (size_t)mt * 16384, sH2, tid);
    __syncthreads();
    const float zv1p = ldcf(w.z1[pp] + m0 + (lane & 15));  // z1_prev, row=lane&15
    {
      f32x4 h1FI = {0,0,0,0}, l1FI = {0,0,0,0}, h1OG = {0,0,0,0}, l1OG = {0,0,0,0};
      f32x4 h2FI = {0,0,0,0}, l2FI = {0,0,0,0}, h2OG = {0,0,0,0}, l2OG = {0,0,0,0};
      const f16* As = sA + lane * 8;
      const f16* Ah = sH2 + lane * 8;
#pragma unroll
      for (int k = 0; k < 16; ++k) {  // h1 @ U11_1
        f16x8 ah = *(const f16x8*)(As + k * 512);
        f16x8 al = *(const f16x8*)(As + (16 + k) * 512);
        f16x8 b0h = ldf(BaH + k * 1024), b0l = ldf(BaL + k * 1024);
        f16x8 b1h = ldf(BaH + k * 1024 + 512), b1l = ldf(BaL + k * 1024 + 512);
        h1FI = MFMA(ah, b0h, h1FI);
        l1FI = MFMA(al, b0h, l1FI); l1FI = MFMA(ah, b0l, l1FI);
        h1OG = MFMA(ah, b1h, h1OG);
        l1OG = MFMA(al, b1h, l1OG); l1OG = MFMA(ah, b1l, l1OG);
      }
      {  // x_t @ W01_1 (both 32-K chunks; goes into the unscaled part)
        const int row = m0 + (lane & 15);
#pragma unroll
        for (int kx = 0; kx < 2; ++kx) {
          const int d = kx * 32 + q * 8;
          const size_t xoff = ((size_t)row * TT + t) * DD + d;
          float xv[8];
          if (F32) {
            const float* px = (const float*)x + xoff;
            float4 rr0 = *(const float4*)px;
            float4 rr1 = *(const float4*)(px + 4);
            xv[0]=rr0.x; xv[1]=rr0.y; xv[2]=rr0.z; xv[3]=rr0.w;
            xv[4]=rr1.x; xv[5]=rr1.y; xv[6]=rr1.z; xv[7]=rr1.w;
          } else {
            const u16* px = (const u16*)x + xoff;
            uint4 raw = *(const uint4*)px;
            u32 rr4[4] = {raw.x, raw.y, raw.z, raw.w};
#pragma unroll
            for (int i = 0; i < 4; ++i) {
              xv[2*i]   = bf2f((u16)(rr4[i] & 0xffffu));
              xv[2*i+1] = bf2f((u16)(rr4[i] >> 16));
            }
          }
          f16x8 axh, axl;
#pragma unroll
          for (int i = 0; i < 8; ++i) {
            f16 h = (f16)xv[i];
            axh[i] = h;
            axl[i] = (f16)((xv[i] - (float)h) * SC);
          }
          f16x8 b0h = ldf(BxH + kx * 1024), b0l = ldf(BxL + kx * 1024);
          f16x8 b1h = ldf(BxH + kx * 1024 + 512), b1l = ldf(BxL + kx * 1024 + 512);
          h1FI = MFMA(axh, b0h, h1FI);
          l1FI = MFMA(axl, b0h, l1FI); l1FI = MFMA(axh, b0l, l1FI);
          h1OG = MFMA(axh, b1h, h1OG);
          l1OG = MFMA(axl, b1h, l1OG); l1OG = MFMA(axh, b1l, l1OG);
        }
      }
#pragma unroll
      for (int k = 0; k < 16; ++k) {  // h2 @ U21_1 (z1-scaled at merge)
        f16x8 ah = *(const f16x8*)(Ah + k * 512);
        f16x8 al = *(const f16x8*)(Ah + (16 + k) * 512);
        f16x8 b0h = ldf(BbH + k * 1024), b0l = ldf(BbL + k * 1024);
        f16x8 b1h = ldf(BbH + k * 1024 + 512), b1l = ldf(BbL + k * 1024 + 512);
        h2FI = MFMA(ah, b0h, h2FI);
        l2FI = MFMA(al, b0h, l2FI); l2FI = MFMA(ah, b0l, l2FI);
        h2OG = MFMA(ah, b1h, h2OG);
        l2OG = MFMA(al, b1h, l2OG); l2OG = MFMA(ah, b1l, l2OG);
      }
      // merge with per-row z1_prev, cross-lane F/I O/G exchange, epilogue
      float vFI[4], vOG[4], oFI[4], oOG[4];
#pragma unroll
      for (int r = 0; r < 4; ++r) {
        const float zr = __shfl(zv1p, q * 4 + r);
        vFI[r] = (h1FI[r] + l1FI[r] * ISC) + zr * (h2FI[r] + l2FI[r] * ISC);
        vOG[r] = (h1OG[r] + l1OG[r] * ISC) + zr * (h2OG[r] + l2OG[r] * ISC);
      }
#pragma unroll
      for (int r = 0; r < 4; ++r) {
        oFI[r] = __shfl_xor(vFI[r], 8);
        oOG[r] = __shfl_xor(vOG[r], 8);
      }
#pragma unroll
      for (int rr = 0; rr < 2; ++rr) {
        const int r = r0 + rr;
        const int b = m0 + q * 4 + r;
        const float sf = (ilane ? oFI[r] : vFI[r]) + b1ff;
        const float si = (ilane ? vFI[r] : oFI[r]) + b1fi;
        const float so = (ilane ? oOG[r] : vOG[r]) + b1fo;
        const float sg = (ilane ? vOG[r] : oOG[r]) + b1fg;
        const float f = sigm(sf), i_ = sigm(si), o = sigm(so), g = tanhf(sg);
        const int idx = b * 512 + jcol;
        const float cold = w.c1[idx];
        const float z1p = __shfl(zv1p, q * 4 + r);
        const float ig = i_ * g;
        const float cn = (z1p != 0.0f) ? ig : (f * cold + ig);
        const float hn = o * tanhf(cn);
        w.c1[idx] = cn;
        const f16 hi = (f16)hn;
        const f16 lo = (f16)((hn - (float)hi) * SC);
        const size_t off = (size_t)mt * 16384 + (size_t)(jcol >> 5) * 512
                         + ((jcol >> 3) & 3) * 128 + (b & 15) * 8 + (jcol & 7);
        stc16(w.H1[pc] + off, hi);
        stc16(w.H1[pc] + off + 8192, lo);
      }
    }
    if (wv < 2) z1_row_lds(w, x, sA, sH2, F32, t, pp, pc, zb0 + wv, lane);
    if (doOut && wv == 2 && t > 0) out_tile_lds(w, out, sA, sH2, F32, t - 1, mt, Jblk, lane);
    gridbar(w.bar, grp, 2 * t + 2);
    // ================= phase B: cell 2 =================
    stage4(w.H1[pc] + (size_t)mt * 16384, sA, tid);  // sH2 keeps H2[pp]
    __syncthreads();
    const float zv1c = ldcf(w.z1[pc] + m0 + (lane & 15));
    const float zv2p = ldcf(w.z2[pp] + m0 + (lane & 15));
    {
      f32x4 aFIh = {0,0,0,0}, aFIl = {0,0,0,0}, aOGh = {0,0,0,0}, aOGl = {0,0,0,0};
      f32x4 bFIh = {0,0,0,0}, bFIl = {0,0,0,0}, bOGh = {0,0,0,0}, bOGl = {0,0,0,0};
      const f16* Ah = sH2 + lane * 8;  // h2_prev
      const f16* An = sA + lane * 8;   // h1_new
#pragma unroll
      for (int k = 0; k < 16; ++k) {  // h2 @ U11_2
        f16x8 ah = *(const f16x8*)(Ah + k * 512);
        f16x8 al = *(const f16x8*)(Ah + (16 + k) * 512);
        f16x8 b0h = ldf(CaH + k * 1024), b0l = ldf(CaL + k * 1024);
        f16x8 b1h = ldf(CaH + k * 1024 + 512), b1l = ldf(CaL + k * 1024 + 512);
        aFIh = MFMA(ah, b0h, aFIh);
        aFIl = MFMA(al, b0h, aFIl); aFIl = MFMA(ah, b0l, aFIl);
        aOGh = MFMA(ah, b1h, aOGh);
        aOGl = MFMA(al, b1h, aOGl); aOGl = MFMA(ah, b1l, aOGl);
      }
#pragma unroll
      for (int k = 0; k < 16; ++k) {  // h1_new @ W01_2 (z1-scaled at merge)
        f16x8 ah = *(const f16x8*)(An + k * 512);
        f16x8 al = *(const f16x8*)(An + (16 + k) * 512);
        f16x8 b0h = ldf(CbH + k * 1024), b0l = ldf(CbL + k * 1024);
        f16x8 b1h = ldf(CbH + k * 1024 + 512), b1l = ldf(CbL + k * 1024 + 512);
        bFIh = MFMA(ah, b0h, bFIh);
        bFIl = MFMA(al, b0h, bFIl); bFIl = MFMA(ah, b0l, bFIl);
        bOGh = MFMA(ah, b1h, bOGh);
        bOGl = MFMA(al, b1h, bOGl); bOGl = MFMA(ah, b1l, bOGl);
      }
      float vFI[4], vOG[4], oFI[4], oOG[4];
#pragma unroll
      for (int r = 0; r < 4; ++r) {
        const float zr = __shfl(zv1c, q * 4 + r);
        vFI[r] = (aFIh[r] + aFIl[r] * ISC) + zr * (bFIh[r] + bFIl[r] * ISC);
        vOG[r] = (aOGh[r] + aOGl[r] * ISC) + zr * (bOGh[r] + bOGl[r] * ISC);
      }
#pragma unroll
      for (int r = 0; r < 4; ++r) {
        oFI[r] = __shfl_xor(vFI[r], 8);
        oOG[r] = __shfl_xor(vOG[r], 8);
      }
#pragma unroll
      for (int rr = 0; rr < 2; ++rr) {
        const int r = r0 + rr;
        const int b = m0 + q * 4 + r;
        const float sf = (ilane ? oFI[r] : vFI[r]) + b2ff;
        const float si = (ilane ? vFI[r] : oFI[r]) + b2fi;
        const float so = (ilane ? oOG[r] : vOG[r]) + b2fo;
        const float sg = (ilane ? vOG[r] : oOG[r]) + b2fg;
        const float f = sigm(sf), i_ = sigm(si), o = sigm(so), g = tanhf(sg);
        const int idx = b * 512 + jcol;
        const float cold = w.c2[idx];
        const float h2old = w.h2m[idx];
        const float z1r = __shfl(zv1c, q * 4 + r);
        const float z2r = __shfl(zv2p, q * 4 + r);
        const float ig = i_ * g;
        const bool zz = (z2r != 0.0f), zb = (z1r != 0.0f);
        const float cn = zz ? ig : (zb ? (f * cold + ig) : cold);  // UPDATE/FLUSH/COPY
        const float th = o * tanhf(cn);
        const float hn = (zz || zb) ? th : h2old;
        w.c2[idx] = cn;
        w.h2m[idx] = hn;
        const f16 hi = (f16)hn;
        const f16 lo = (f16)((hn - (float)hi) * SC);
        const size_t off = (size_t)mt * 16384 + (size_t)(jcol >> 5) * 512
                         + ((jcol >> 3) & 3) * 128 + (b & 15) * 8 + (jcol & 7);
        stc16(w.H2[pc] + off, hi);
        stc16(w.H2[pc] + off + 8192, lo);
      }
    }
    if (wv < 2) z2_row_lds(w, sH2, sA, pc, zb0 + wv, lane);
    gridbar(w.bar, grp, 2 * t + 3);
  }
  // final output row (t = 511, parity 1)
  if (doOut && wv == 2) out_tile_g(w, out, F32, 1, 511, mt, Jblk, lane);
}

extern "C" void kernel_launch(void* const* d_in, const int* in_sizes, int n_in,
                              void* d_out, int out_size, void* d_ws, size_t ws_size,
                              hipStream_t stream)
{
  (void)in_sizes; (void)n_in; (void)out_size; (void)ws_size;
  const void* x     = d_in[0];
  const void* U11_1 = d_in[1];
  const void* U21_1 = d_in[2];
  const void* W01_1 = d_in[3];
  const void* bias1 = d_in[4];
  const void* U11_2 = d_in[5];
  const void* W01_2 = d_in[6];
  const void* bias2 = d_in[7];
  const void* l1W   = d_in[8];
  const void* l1b   = d_in[9];
  const void* l2W   = d_in[10];
  const void* l2b   = d_in[11];

  char* base = (char*)d_ws;
  size_t o = 0;
  auto take = [&](size_t bytes) -> char* {
    char* p = base + o;
    o = (o + bytes + 1023) & ~(size_t)1023;
    return p;
  };
  WS w;
  w.PB1aH = (f16*)take(1048576 * 2); w.PB1aL = (f16*)take(1048576 * 2);
  w.PB1bH = (f16*)take(1048576 * 2); w.PB1bL = (f16*)take(1048576 * 2);
  w.PB2aH = (f16*)take(1048576 * 2); w.PB2aL = (f16*)take(1048576 * 2);
  w.PB2bH = (f16*)take(1048576 * 2); w.PB2bL = (f16*)take(1048576 * 2);
  w.PB1xH = (f16*)take(131072 * 2);  w.PB1xL = (f16*)take(131072 * 2);
  w.PBo   = (f16*)take(65536 * 2);
  for (int i = 0; i < 2; ++i) w.H1[i] = (f16*)take(262144 * 2);
  for (int i = 0; i < 2; ++i) w.H2[i] = (f16*)take(262144 * 2);
  w.c1  = (float*)take(131072 * 4);
  w.c2  = (float*)take(131072 * 4);
  w.h2m = (float*)take(131072 * 4);
  w.wz1 = (float*)take(2112 * 4);
  w.wz2 = (float*)take(2048 * 4);
  w.b1f = (float*)take(2049 * 4);
  w.b2f = (float*)take(2049 * 4);
  w.bof = (float*)take(64 * 4);
  for (int i = 0; i < 2; ++i) w.z1[i] = (float*)take(256 * 4);
  for (int i = 0; i < 2; ++i) w.z2[i] = (float*)take(256 * 4);
  w.bar = (int*)take(2048 * 4);
  w.flag = (int*)take(4 * 4);
  // total ~20.5 MB of d_ws

  detect_kernel<<<1, 64, 0, stream>>>((const u16*)x, w.flag);
  pack_kernel<<<(NPACK + 255) / 256, 256, 0, stream>>>(
      U11_1, U21_1, W01_1, bias1, U11_2, W01_2, bias2, l1W, l1b, l2W, l2b, w);
  init_kernel<<<2570, 256, 0, stream>>>(w);
  persist<<<128, 512, 0, stream>>>(x, d_out, w);
}

// Round 9
// 15747.108 us; speedup vs baseline: 3.1721x; 3.1721x over previous
//
#include <hip/hip_runtime.h>

typedef unsigned short u16;
typedef unsigned int u32;
typedef _Float16 f16;
typedef __attribute__((ext_vector_type(8))) _Float16 f16x8;
typedef __attribute__((ext_vector_type(4))) float f32x4;

#define TT 512
#define DD 64
#define SC 2048.0f
#define ISC (1.0f / 2048.0f)

// Activation buffers (H1/H2/Z): f16 hi/lo-split pairs, MFMA-fragment layout:
// [mtile(16)][ks(32: 0-15 hi, 16-31 lo*2^11)][1KB frag]; frag elem
// (m=lane&15, k=quad*8+i) at quad*128 + m*8 + (k&7). Weight B-frags likewise
// split into H and L (L pre-scaled by 2^11; true value = H + L/2^11).
// Two dispatches per timestep: the dispatch boundary provides HW-managed
// L2 coherence (writeback+invalidate), so all loads are plain cached at
// full width. (Persistent/MALL variants measured slower: uncached exchange
// is bound at ~8G line-req/s ≈ 20-50us/step vs ~10us dispatch overhead.)
struct WS {
  f16 *PB1aH, *PB1aL, *PB1bH, *PB1bL, *PB1xH, *PB1xL;
  f16 *PB2aH, *PB2aL, *PB2bH, *PB2bL, *PBo;
  float *wz1, *wz2, *b1f, *b2f, *bof;
  f16 *H1[2], *H2[2], *Z[2];
  float *c1, *c2, *h2m;
  float *z1[2], *z2[2];
  int *flag;  // 1 = inputs are float32, 0 = inputs are bf16
};

__device__ __forceinline__ float bf2f(u16 u) { return __uint_as_float(((u32)u) << 16); }
__device__ __forceinline__ u16 f2bf(float f) {
  u32 u = __float_as_uint(f);
  u += 0x7fffu + ((u >> 16) & 1u);
  return (u16)(u >> 16);
}
__device__ __forceinline__ float ldw(const void* p, size_t i, int f32) {
  return f32 ? ((const float*)p)[i] : bf2f(((const u16*)p)[i]);
}
__device__ __forceinline__ float sigm(float x) { return 1.0f / (1.0f + expf(-x)); }
__device__ __forceinline__ f16x8 ldf(const f16* p) { return *(const f16x8*)p; }

// fp64 wave shuffle (manual hi/lo split)
__device__ __forceinline__ double shfl_down_dbl(double v, int off) {
  const int lo = __shfl_down(__double2loint(v), off);
  const int hi = __shfl_down(__double2hiint(v), off);
  return __hiloint2double(hi, lo);
}

#define MFMA(a, b, c) __builtin_amdgcn_mfma_f32_16x16x32_f16(a, b, c, 0, 0, 0)

// ---------------- dtype detection ----------------
__global__ void detect_kernel(const u16* __restrict__ x, int* __restrict__ flag)
{
  int tid = threadIdx.x;  // 64 threads
  int cnt = 0;
  for (int i = tid; i < 8192; i += 64) {
    int e = (x[i] >> 7) & 0xFF;
    cnt += (e >= 0xC0 || (e != 0 && e < 0x30)) ? 1 : 0;
  }
#pragma unroll
  for (int off = 32; off; off >>= 1) cnt += __shfl_down(cnt, off);
  if (tid == 0) *flag = (cnt > 100) ? 1 : 0;
}

// ---------------- prologue: weight packing ----------------
__device__ __forceinline__ void packGate(const void* __restrict__ U,
                                         f16* __restrict__ dstH, f16* __restrict__ dstL,
                                         int g, int KS, int F32) {
  int lane = g & 63;
  int rest = g >> 6;
  int t2 = rest & 1; rest >>= 1;
  int ks = rest % KS;
  int J  = rest / KS;
  int q = lane >> 4, n = lane & 15;
  int j = J * 8 + (n & 7);
  int c = (t2 * 2 + (n >> 3)) * 512 + j;
  int kb = ks * 32 + q * 8;
  f16 vh[8], vl[8];
#pragma unroll
  for (int i = 0; i < 8; ++i) {
    float v = ldw(U, (size_t)(kb + i) * 2049 + c, F32);
    f16 h = (f16)v;
    vh[i] = h;
    vl[i] = (f16)((v - (float)h) * SC);
  }
  *(f16x8*)(dstH + (size_t)g * 8) = *(f16x8*)vh;
  *(f16x8*)(dstL + (size_t)g * 8) = *(f16x8*)vl;
}

#define NPACK (4 * 131072 + 16384 + 8192 + 2112 + 2048 + 2049 + 2049 + 64)

__global__ __launch_bounds__(256) void pack_kernel(
    const void* __restrict__ U11_1, const void* __restrict__ U21_1,
    const void* __restrict__ W01_1, const void* __restrict__ bias1,
    const void* __restrict__ U11_2, const void* __restrict__ W01_2,
    const void* __restrict__ bias2, const void* __restrict__ l1W,
    const void* __restrict__ l1b, const void* __restrict__ l2W,
    const void* __restrict__ l2b, WS w)
{
  const int F32 = *w.flag;
  int gid = blockIdx.x * 256 + threadIdx.x;
  const int NG = 131072;
  if (gid < NG) { packGate(U11_1, w.PB1aH, w.PB1aL, gid, 16, F32); return; }
  gid -= NG;
  if (gid < NG) { packGate(U21_1, w.PB1bH, w.PB1bL, gid, 16, F32); return; }
  gid -= NG;
  if (gid < NG) { packGate(U11_2, w.PB2aH, w.PB2aL, gid, 16, F32); return; }
  gid -= NG;
  if (gid < NG) { packGate(W01_2, w.PB2bH, w.PB2bL, gid, 16, F32); return; }
  gid -= NG;
  if (gid < 16384) { packGate(W01_1, w.PB1xH, w.PB1xL, gid, 2, F32); return; }
  gid -= 16384;
  if (gid < 8192) {  // PBo (hi only): [w4][ks 0..31][lane][8]
    int lane = gid & 63;
    int rest = gid >> 6;
    int ks = rest & 31;
    int w4 = rest >> 5;
    int q = lane >> 4;
    int d = w4 * 16 + (lane & 15);
    int kb = ks * 32 + q * 8;
    f16 v[8];
#pragma unroll
    for (int i = 0; i < 8; ++i) {
      int k = kb + i;
      float s = (k < 512) ? ldw(l1W, (size_t)d * 512 + k, F32)
                          : ldw(l2W, (size_t)d * 512 + (k - 512), F32);
      v[i] = (f16)s;
    }
    *(f16x8*)(w.PBo + (size_t)gid * 8) = *(f16x8*)v;
    return;
  }
  gid -= 8192;
  if (gid < 2112) {  // z-column weights, cell1 (fp32 exact)
    int i = gid; float s;
    if (i < 512)       s = ldw(U11_1, (size_t)i * 2049 + 2048, F32);
    else if (i < 1024) s = ldw(U11_1, (size_t)(i - 512) * 2049 + 2048, F32);
    else if (i < 1536) s = ldw(U21_1, (size_t)(i - 1024) * 2049 + 2048, F32);
    else if (i < 2048) s = ldw(U21_1, (size_t)(i - 1536) * 2049 + 2048, F32);
    else               s = ldw(W01_1, (size_t)(i - 2048) * 2049 + 2048, F32);
    w.wz1[i] = s; return;
  }
  gid -= 2112;
  if (gid < 2048) {  // z-column weights, cell2
    int i = gid; float s;
    if (i < 512)       s = ldw(U11_2, (size_t)i * 2049 + 2048, F32);
    else if (i < 1024) s = ldw(U11_2, (size_t)(i - 512) * 2049 + 2048, F32);
    else if (i < 1536) s = ldw(W01_2, (size_t)(i - 1024) * 2049 + 2048, F32);
    else               s = ldw(W01_2, (size_t)(i - 1536) * 2049 + 2048, F32);
    w.wz2[i] = s; return;
  }
  gid -= 2048;
  if (gid < 2049) { w.b1f[gid] = ldw(bias1, gid, F32); return; }
  gid -= 2049;
  if (gid < 2049) { w.b2f[gid] = ldw(bias2, gid, F32); return; }
  gid -= 2049;
  if (gid < 64) { w.bof[gid] = ldw(l1b, gid, F32) + ldw(l2b, gid, F32); return; }
}

__global__ __launch_bounds__(256) void init_kernel(WS w)
{
  size_t id = (size_t)blockIdx.x * 256 + threadIdx.x;
  const size_t nw = 131072;  // u32 words per f16 state buffer
  if (id < 3 * nw) {
    u32* p = (id < nw) ? (u32*)w.H1[1] : (id < 2 * nw) ? (u32*)w.H2[1] : (u32*)w.Z[1];
    p[id % nw] = 0u;
    return;
  }
  id -= 3 * nw;
  const size_t nf = 131072;
  if (id < 3 * nf) {
    float* p = (id < nf) ? w.c1 : (id < 2 * nf) ? w.c2 : w.h2m;
    p[id % nf] = 0.0f;
    return;
  }
  id -= 3 * nf;
  if (id < 512) {
    ((id < 256) ? w.z1[1] : w.z2[1])[id & 255] = 0.0f;
  }
}

// ---------------- output tile: out[b,twrite,:] = h1@l1W^T + h2@l2W^T + bias ----
__device__ __forceinline__ void out_tile(const WS& w, void* __restrict__ out, int F32,
                                         int pq, int twrite, int ot, int wv, int lane)
{
  const f16* A1 = w.H1[pq] + (size_t)ot * 16384 + lane * 8;  // hi sections only
  const f16* A2 = w.H2[pq] + (size_t)ot * 16384 + lane * 8;
  const f16* Bo = w.PBo + (size_t)wv * 16384 + lane * 8;
  f32x4 acc = {0.f, 0.f, 0.f, 0.f};
#pragma unroll
  for (int k = 0; k < 16; ++k) acc = MFMA(ldf(A1 + k * 512), ldf(Bo + k * 512), acc);
#pragma unroll
  for (int k = 0; k < 16; ++k) acc = MFMA(ldf(A2 + k * 512), ldf(Bo + (16 + k) * 512), acc);
  const int q = lane >> 4;
  const int d = wv * 16 + (lane & 15);
  const float bias = w.bof[d];
#pragma unroll
  for (int r = 0; r < 4; ++r) {
    const int b = ot * 16 + q * 4 + r;
    const size_t idx = ((size_t)b * TT + twrite) * DD + d;
    const float val = acc[r] + bias;
    if (F32) ((float*)out)[idx] = val;
    else     ((u16*)out)[idx] = f2bf(val);
  }
}

// ---------------- step1: cell 1 (GEMM + gates + z1) + out_{t-1} ----------------
// Grid 544, AUX FIRST so small blocks overlap the GEMM wave instead of
// serializing after it: blocks [0,16) z1-logit (4 rows/wave), [16,32)
// out_{t-1}, [32,544) GEMM (waves (mhalf, kh): kh splits K-work; partials
// merged through LDS). (bid-32)%8 == J%8 preserves XCD weight locality.
__global__ __launch_bounds__(256) void step1(const void* __restrict__ x,
                                             void* __restrict__ out, WS w, int t)
{
  __shared__ float ex[2][2][64][9];  // [mhalf][kh][lane][0..3 FI, 4..7 OG] (+pad)
  const int F32 = *w.flag;
  const int pc = t & 1, pp = pc ^ 1;
  const int bid = blockIdx.x;
  const int tid = threadIdx.x;
  const int lane = tid & 63, wv = tid >> 6;

  if (bid >= 32) {
    const int gb = bid - 32;
    const int J = gb & 63, mq = gb >> 6;     // gb%8 == J%8 -> XCD weight locality
    const int mhalf = wv & 1, kh = wv >> 1;
    const int J2 = J;
    const int mtile = mq * 2 + mhalf;
    const int m0 = mtile * 16;
    f32x4 hFI = {0.f,0.f,0.f,0.f}, lFI = {0.f,0.f,0.f,0.f};
    f32x4 hOG = {0.f,0.f,0.f,0.f}, lOG = {0.f,0.f,0.f,0.f};
    if (kh == 0) {
      const f16* A1 = w.H1[pp] + (size_t)mtile * 16384 + lane * 8;
      const f16* BaH = w.PB1aH + (size_t)J2 * 16384 + lane * 8;
      const f16* BaL = w.PB1aL + (size_t)J2 * 16384 + lane * 8;
#pragma unroll
      for (int k = 0; k < 16; ++k) {  // h1 @ U11_1, full hi/lo product (3 terms)
        f16x8 ah = ldf(A1 + k * 512);
        f16x8 al = ldf(A1 + (16 + k) * 512);
        f16x8 b0h = ldf(BaH + k * 1024), b0l = ldf(BaL + k * 1024);
        f16x8 b1h = ldf(BaH + k * 1024 + 512), b1l = ldf(BaL + k * 1024 + 512);
        hFI = MFMA(ah, b0h, hFI);
        lFI = MFMA(al, b0h, lFI); lFI = MFMA(ah, b0l, lFI);
        hOG = MFMA(ah, b1h, hOG);
        lOG = MFMA(al, b1h, lOG); lOG = MFMA(ah, b1l, lOG);
      }
    } else {
      const f16* AZ = w.Z[pp] + (size_t)mtile * 16384 + lane * 8;
      const f16* BbH = w.PB1bH + (size_t)J2 * 16384 + lane * 8;
      const f16* BbL = w.PB1bL + (size_t)J2 * 16384 + lane * 8;
#pragma unroll
      for (int k = 0; k < 16; ++k) {  // (z1_prev * h2) @ U21_1
        f16x8 ah = ldf(AZ + k * 512);
        f16x8 al = ldf(AZ + (16 + k) * 512);
        f16x8 b0h = ldf(BbH + k * 1024), b0l = ldf(BbL + k * 1024);
        f16x8 b1h = ldf(BbH + k * 1024 + 512), b1l = ldf(BbL + k * 1024 + 512);
        hFI = MFMA(ah, b0h, hFI);
        lFI = MFMA(al, b0h, lFI); lFI = MFMA(ah, b0l, lFI);
        hOG = MFMA(ah, b1h, hOG);
        lOG = MFMA(al, b1h, lOG); lOG = MFMA(ah, b1l, lOG);
      }
    }
    {  // x_t @ W01_1 with hi/lo split of x; sub-tile kx = kh
      const f16* BxH = w.PB1xH + (size_t)J2 * 2048 + lane * 8;
      const f16* BxL = w.PB1xL + (size_t)J2 * 2048 + lane * 8;
      const int row = m0 + (lane & 15);
      const int qq = lane >> 4;
      const int kx = kh;
      const int d = kx * 32 + qq * 8;
      const size_t xoff = ((size_t)row * TT + t) * DD + d;
      float xv[8];
      if (F32) {
        const float* px = (const float*)x + xoff;
        float4 r0 = *(const float4*)px;
        float4 r1 = *(const float4*)(px + 4);
        xv[0]=r0.x; xv[1]=r0.y; xv[2]=r0.z; xv[3]=r0.w;
        xv[4]=r1.x; xv[5]=r1.y; xv[6]=r1.z; xv[7]=r1.w;
      } else {
        const u16* px = (const u16*)x + xoff;
        uint4 raw = *(const uint4*)px;
        u32 rr4[4] = {raw.x, raw.y, raw.z, raw.w};
#pragma unroll
        for (int i = 0; i < 4; ++i) {
          xv[2*i]   = bf2f((u16)(rr4[i] & 0xffffu));
          xv[2*i+1] = bf2f((u16)(rr4[i] >> 16));
        }
      }
      f16x8 axh, axl;
#pragma unroll
      for (int i = 0; i < 8; ++i) {
        f16 h = (f16)xv[i];
        axh[i] = h;
        axl[i] = (f16)((xv[i] - (float)h) * SC);
      }
      f16x8 b0h = ldf(BxH + kx * 1024), b0l = ldf(BxL + kx * 1024);
      f16x8 b1h = ldf(BxH + kx * 1024 + 512), b1l = ldf(BxL + kx * 1024 + 512);
      hFI = MFMA(axh, b0h, hFI);
      lFI = MFMA(axl, b0h, lFI); lFI = MFMA(axh, b0l, lFI);
      hOG = MFMA(axh, b1h, hOG);
      lOG = MFMA(axl, b1h, lOG); lOG = MFMA(axh, b1l, lOG);
    }
    // combine hi/lo partials and exchange across the kh wave-pair
#pragma unroll
    for (int r = 0; r < 4; ++r) {
      ex[mhalf][kh][lane][r]     = hFI[r] + lFI[r] * ISC;
      ex[mhalf][kh][lane][4 + r] = hOG[r] + lOG[r] * ISC;
    }
    __syncthreads();
    const float aFIlo = ex[mhalf][0][lane][kh]     + ex[mhalf][1][lane][kh];
    const float aFIhi = ex[mhalf][0][lane][2 + kh] + ex[mhalf][1][lane][2 + kh];
    const float aOGlo = ex[mhalf][0][lane][4 + kh] + ex[mhalf][1][lane][4 + kh];
    const float aOGhi = ex[mhalf][0][lane][6 + kh] + ex[mhalf][1][lane][6 + kh];
    const float oFIlo = __shfl_xor(aFIlo, 8), oFIhi = __shfl_xor(aFIhi, 8);
    const float oOGlo = __shfl_xor(aOGlo, 8), oOGhi = __shfl_xor(aOGhi, 8);
    // fused cell-1 epilogue (z = z1_prev, z_bottom = 1 -> h = o*tanh(c));
    // this wave handles row-offset r = (ilane?2:0) + kh
    const int q = lane >> 4;
    const int jcol = J2 * 8 + (lane & 7);
    const bool ilane = (lane & 8) != 0;
    const float bf_ = w.b1f[jcol], bi_ = w.b1f[512 + jcol];
    const float bo_ = w.b1f[1024 + jcol], bg_ = w.b1f[1536 + jcol];
    const int r = (ilane ? 2 : 0) + kh;
    const int b = m0 + q * 4 + r;
    const float sf = (ilane ? oFIhi : aFIlo) + bf_;
    const float si = (ilane ? aFIhi : oFIlo) + bi_;
    const float so = (ilane ? oOGhi : aOGlo) + bo_;
    const float sg = (ilane ? aOGhi : oOGlo) + bg_;
    const float f = sigm(sf), i_ = sigm(si), o = sigm(so), g = tanhf(sg);
    const int idx = b * 512 + jcol;
    const float cold = w.c1[idx];
    const float z1p = w.z1[pp][b];
    const float ig = i_ * g;
    const float cn = (z1p != 0.0f) ? ig : (f * cold + ig);
    const float hn = o * tanhf(cn);
    w.c1[idx] = cn;
    const f16 hi = (f16)hn;
    const f16 lo = (f16)((hn - (float)hi) * SC);
    const size_t off = (size_t)(b >> 4) * 16384 + (size_t)(jcol >> 5) * 512
                     + ((jcol >> 3) & 3) * 128 + (b & 15) * 8 + (jcol & 7);
    w.H1[pc][off] = hi;
    w.H1[pc][off + 8192] = lo;
  } else if (bid < 16) {
    // z1 logit: wave handles 4 rows serially; fp64 partials + wave shuffle-reduce
    const int bz = bid;
    const int ks = lane >> 2;   // 0..15
    const int qq = lane & 3;    // 0..3
    const int j = ks * 32 + qq * 8;
    for (int rr = 0; rr < 4; ++rr) {
      const int b = bz * 16 + wv * 4 + rr;
      const size_t fro = (size_t)(b >> 4) * 16384 + (b & 15) * 8
                       + (size_t)ks * 512 + (size_t)qq * 128;
      const f16* pa = w.H1[pp] + fro;
      const f16* pz = w.Z[pp]  + fro;
      f16x8 h8 = ldf(pa), l8 = ldf(pa + 8192);
      f16x8 h8z = ldf(pz), l8z = ldf(pz + 8192);
      double acc = 0.0;
#pragma unroll
      for (int i = 0; i < 8; ++i) {
        double ha = (double)(float)h8[i]  + (double)(float)l8[i]  * (1.0 / 2048.0);
        double hz = (double)(float)h8z[i] + (double)(float)l8z[i] * (1.0 / 2048.0);
        acc += ha * (double)w.wz1[j + i];
        acc += hz * (double)w.wz1[1024 + j + i];
      }
      {  // x part: lane d = lane handles one element
        float xv = ldw(x, ((size_t)b * TT + t) * DD + lane, F32);
        acc += (double)xv * (double)w.wz1[2048 + lane];
      }
#pragma unroll
      for (int off = 32; off; off >>= 1) acc += shfl_down_dbl(acc, off);
      if (lane == 0) {
        double s = acc + (double)w.b1f[2048];
        float sz = (float)s;
        float zh = (sz + 1.0f) * 0.5f;  // round-half-even(zh) == (zh > 0.5)
        w.z1[pc][b] = (zh > 0.5f) ? 1.0f : 0.0f;
      }
    }
  } else {
    if (t == 0) return;  // out_{t-1} piggyback
    out_tile(w, out, F32, pp, t - 1, bid - 16, wv, lane);
  }
}

// ---------------- step2: cell 2 (GEMM + gates + z2) ----------------
// Grid 528, AUX FIRST: blocks [0,16) z2-logit, [16,528) GEMM (waves
// (mhalf, kh): kh0 = h2@U11_2, kh1 = h1_new@W01_2 pre-scaled by z1_new).
__global__ __launch_bounds__(256) void step2(WS w, int t)
{
  __shared__ float ex[2][2][64][9];
  const int pc = t & 1, pp = pc ^ 1;
  const int bid = blockIdx.x;
  const int tid = threadIdx.x;
  const int lane = tid & 63, wv = tid >> 6;
  if (bid >= 16) {
    const int gb = bid - 16;
    const int J = gb & 63, mq = gb >> 6;
    const int mhalf = wv & 1, kh = wv >> 1;
    const int mtile = mq * 2 + mhalf;
    const int m0 = mtile * 16;
    const int q = lane >> 4;
    f32x4 pFIh = {0.f,0.f,0.f,0.f}, pFIl = {0.f,0.f,0.f,0.f};
    f32x4 pOGh = {0.f,0.f,0.f,0.f}, pOGl = {0.f,0.f,0.f,0.f};
    if (kh == 0) {
      const f16* Aa = w.H2[pp] + (size_t)mtile * 16384 + lane * 8;  // h2_prev
      const f16* BaH = w.PB2aH + (size_t)J * 16384 + lane * 8;
      const f16* BaL = w.PB2aL + (size_t)J * 16384 + lane * 8;
#pragma unroll
      for (int k = 0; k < 16; ++k) {  // h2 @ U11_2
        f16x8 ah = ldf(Aa + k * 512);
        f16x8 al = ldf(Aa + (16 + k) * 512);
        f16x8 b0h = ldf(BaH + k * 1024), b0l = ldf(BaL + k * 1024);
        f16x8 b1h = ldf(BaH + k * 1024 + 512), b1l = ldf(BaL + k * 1024 + 512);
        pFIh = MFMA(ah, b0h, pFIh);
        pFIl = MFMA(al, b0h, pFIl); pFIl = MFMA(ah, b0l, pFIl);
        pOGh = MFMA(ah, b1h, pOGh);
        pOGl = MFMA(al, b1h, pOGl); pOGl = MFMA(ah, b1l, pOGl);
      }
    } else {
      const f16* Ab = w.H1[pc] + (size_t)mtile * 16384 + lane * 8;  // h1_new
      const f16* BbH = w.PB2bH + (size_t)J * 16384 + lane * 8;
      const f16* BbL = w.PB2bL + (size_t)J * 16384 + lane * 8;
#pragma unroll
      for (int k = 0; k < 16; ++k) {  // h1_new @ W01_2 (z1-scaled below)
        f16x8 ah = ldf(Ab + k * 512);
        f16x8 al = ldf(Ab + (16 + k) * 512);
        f16x8 b0h = ldf(BbH + k * 1024), b0l = ldf(BbL + k * 1024);
        f16x8 b1h = ldf(BbH + k * 1024 + 512), b1l = ldf(BbL + k * 1024 + 512);
        pFIh = MFMA(ah, b0h, pFIh);
        pFIl = MFMA(al, b0h, pFIl); pFIl = MFMA(ah, b0l, pFIl);
        pOGh = MFMA(ah, b1h, pOGh);
        pOGl = MFMA(al, b1h, pOGl); pOGl = MFMA(ah, b1l, pOGl);
      }
    }
    // combine hi/lo; the kh1 (W01_2) partial is scaled by z1_new per row
#pragma unroll
    for (int r = 0; r < 4; ++r) {
      float vFI = pFIh[r] + pFIl[r] * ISC;
      float vOG = pOGh[r] + pOGl[r] * ISC;
      if (kh == 1) {
        const float z1r = w.z1[pc][m0 + q * 4 + r];
        vFI *= z1r; vOG *= z1r;
      }
      ex[mhalf][kh][lane][r]     = vFI;
      ex[mhalf][kh][lane][4 + r] = vOG;
    }
    __syncthreads();
    const float aFIlo = ex[mhalf][0][lane][kh]     + ex[mhalf][1][lane][kh];
    const float aFIhi = ex[mhalf][0][lane][2 + kh] + ex[mhalf][1][lane][2 + kh];
    const float aOGlo = ex[mhalf][0][lane][4 + kh] + ex[mhalf][1][lane][4 + kh];
    const float aOGhi = ex[mhalf][0][lane][6 + kh] + ex[mhalf][1][lane][6 + kh];
    const float oFIlo = __shfl_xor(aFIlo, 8), oFIhi = __shfl_xor(aFIhi, 8);
    const float oOGlo = __shfl_xor(aOGlo, 8), oOGhi = __shfl_xor(aOGhi, 8);
    const int jcol = J * 8 + (lane & 7);
    const bool ilane = (lane & 8) != 0;
    const float bf_ = w.b2f[jcol], bi_ = w.b2f[512 + jcol];
    const float bo_ = w.b2f[1024 + jcol], bg_ = w.b2f[1536 + jcol];
    const int r = (ilane ? 2 : 0) + kh;
    const int b = m0 + q * 4 + r;
    const float sf = (ilane ? oFIhi : aFIlo) + bf_;
    const float si = (ilane ? aFIhi : oFIlo) + bi_;
    const float so = (ilane ? oOGhi : aOGlo) + bo_;
    const float sg = (ilane ? aOGhi : oOGlo) + bg_;
    const float f = sigm(sf), i_ = sigm(si), o = sigm(so), g = tanhf(sg);
    const int idx = b * 512 + jcol;
    const float cold = w.c2[idx];
    const float h2old = w.h2m[idx];
    const float z1r = w.z1[pc][b];
    const float z2r = w.z2[pp][b];
    const float ig = i_ * g;
    const bool zz = (z2r != 0.0f), zb = (z1r != 0.0f);
    const float cn = zz ? ig : (zb ? (f * cold + ig) : cold);  // UPDATE/FLUSH/COPY
    const float th = o * tanhf(cn);
    const float hn = (zz || zb) ? th : h2old;
    w.c2[idx] = cn;
    w.h2m[idx] = hn;
    const f16 hi = (f16)hn;
    const f16 lo = (f16)((hn - (float)hi) * SC);
    const size_t off = (size_t)(b >> 4) * 16384 + (size_t)(jcol >> 5) * 512
                     + ((jcol >> 3) & 3) * 128 + (b & 15) * 8 + (jcol & 7);
    w.H2[pc][off] = hi;
    w.H2[pc][off + 8192] = lo;
    w.Z[pc][off]        = zb ? hi : (f16)0.f;  // z1_new * h2_new for next step1
    w.Z[pc][off + 8192] = zb ? lo : (f16)0.f;
  } else {
    // z2 logit: wave handles 4 rows serially; fp64 partials + shuffle-reduce
    const int bz = bid;
    const int ks = lane >> 2;
    const int qq = lane & 3;
    const int j = ks * 32 + qq * 8;
    for (int rr = 0; rr < 4; ++rr) {
      const int b = bz * 16 + wv * 4 + rr;
      const size_t fro = (size_t)(b >> 4) * 16384 + (b & 15) * 8
                       + (size_t)ks * 512 + (size_t)qq * 128;
      const f16* pa = w.H2[pp] + fro;
      const f16* pb = w.H1[pc] + fro;
      f16x8 h8  = ldf(pa), l8  = ldf(pa + 8192);
      f16x8 h8b = ldf(pb), l8b = ldf(pb + 8192);
      double da = 0.0, db = 0.0;
#pragma unroll
      for (int i = 0; i < 8; ++i) {
        double ha = (double)(float)h8[i]  + (double)(float)l8[i]  * (1.0 / 2048.0);
        double hb = (double)(float)h8b[i] + (double)(float)l8b[i] * (1.0 / 2048.0);
        da += ha * (double)w.wz2[j + i];
        db += hb * (double)w.wz2[1024 + j + i];
      }
#pragma unroll
      for (int off = 32; off; off >>= 1) {
        da += shfl_down_dbl(da, off);
        db += shfl_down_dbl(db, off);
      }
      if (lane == 0) {
        const double z1n = (double)w.z1[pc][b];
        double s = da + z1n * db + (double)w.b2f[2048];
        float sz = (float)s;
        w.z2[pc][b] = (((sz + 1.0f) * 0.5f) > 0.5f) ? 1.0f : 0.0f;
      }
    }
  }
}

__global__ __launch_bounds__(256) void out_final(WS w, void* __restrict__ out)
{
  const int F32 = *w.flag;
  const int lane = threadIdx.x & 63, wv = threadIdx.x >> 6;
  out_tile(w, out, F32, 1, 511, blockIdx.x, wv, lane);  // parity of t=511 is 1
}

extern "C" void kernel_launch(void* const* d_in, const int* in_sizes, int n_in,
                              void* d_out, int out_size, void* d_ws, size_t ws_size,
                              hipStream_t stream)
{
  (void)in_sizes; (void)n_in; (void)out_size; (void)ws_size;
  const void* x     = d_in[0];
  const void* U11_1 = d_in[1];
  const void* U21_1 = d_in[2];
  const void* W01_1 = d_in[3];
  const void* bias1 = d_in[4];
  const void* U11_2 = d_in[5];
  const void* W01_2 = d_in[6];
  const void* bias2 = d_in[7];
  const void* l1W   = d_in[8];
  const void* l1b   = d_in[9];
  const void* l2W   = d_in[10];
  const void* l2b   = d_in[11];

  char* base = (char*)d_ws;
  size_t o = 0;
  auto take = [&](size_t bytes) -> char* {
    char* p = base + o;
    o = (o + bytes + 1023) & ~(size_t)1023;
    return p;
  };
  WS w;
  w.PB1aH = (f16*)take(1048576 * 2); w.PB1aL = (f16*)take(1048576 * 2);
  w.PB1bH = (f16*)take(1048576 * 2); w.PB1bL = (f16*)take(1048576 * 2);
  w.PB2aH = (f16*)take(1048576 * 2); w.PB2aL = (f16*)take(1048576 * 2);
  w.PB2bH = (f16*)take(1048576 * 2); w.PB2bL = (f16*)take(1048576 * 2);
  w.PB1xH = (f16*)take(131072 * 2);  w.PB1xL = (f16*)take(131072 * 2);
  w.PBo   = (f16*)take(65536 * 2);
  for (int i = 0; i < 2; ++i) w.H1[i] = (f16*)take(262144 * 2);
  for (int i = 0; i < 2; ++i) w.H2[i] = (f16*)take(262144 * 2);
  for (int i = 0; i < 2; ++i) w.Z[i]  = (f16*)take(262144 * 2);
  w.c1  = (float*)take(131072 * 4);
  w.c2  = (float*)take(131072 * 4);
  w.h2m = (float*)take(131072 * 4);
  w.wz1 = (float*)take(2112 * 4);
  w.wz2 = (float*)take(2048 * 4);
  w.b1f = (float*)take(2049 * 4);
  w.b2f = (float*)take(2049 * 4);
  w.bof = (float*)take(64 * 4);
  for (int i = 0; i < 2; ++i) w.z1[i] = (float*)take(256 * 4);
  for (int i = 0; i < 2; ++i) w.z2[i] = (float*)take(256 * 4);
  w.flag = (int*)take(4 * 4);
  // total ~21.5 MB of d_ws

  detect_kernel<<<1, 64, 0, stream>>>((const u16*)x, w.flag);
  pack_kernel<<<(NPACK + 255) / 256, 256, 0, stream>>>(
      U11_1, U21_1, W01_1, bias1, U11_2, W01_2, bias2, l1W, l1b, l2W, l2b, w);
  init_kernel<<<3074, 256, 0, stream>>>(w);
  for (int t = 0; t < 512; ++t) {
    step1<<<544, 256, 0, stream>>>(x, d_out, w, t);
    step2<<<528, 256, 0, stream>>>(w, t);
  }
  out_final<<<16, 256, 0, stream>>>(w, d_out);
}